// Round 14
// baseline (4388.516 us; speedup 1.0000x reference)
//
#include <hip/hip_runtime.h>

// LSTM T=512,B=128,D=H=1024. R14: counted-vmcnt everywhere.
// gemm_zx: 512thr, 128x128, BK=64, 16 phases, 4 bufs depth-3 (R13 skeleton),
//   XCD-bijective swizzle. Step: BK=256, 4 phases, 3 bufs depth-2,
//   waits 6,6,6,0. Epilogue identical to R13 (proven).
// Gate interleave: n = hcol*4+gate -> f/i/g/o in lanes l^{0,1,2,3}.

#define TT 512
#define BB 128

typedef __attribute__((ext_vector_type(8))) short short8;
typedef __attribute__((ext_vector_type(4))) float f32x4;

// ws layout (main tier) — bound proven by R11/R13 passing runs
#define WX_OFF   0u                  // [4096][1024] bf16 = 8 MiB
#define WH_OFF   8388608u            // [4096][1024] bf16 = 8 MiB
#define H_OFF    16777216u           // 2 x [128][1024] bf16 = 512 KiB
#define C_OFF    17301504u           // [32][1024][4] f32 = 512 KiB (blocked)
#define XBF_OFF  17825792u           // quarter X: [128*128][1024] bf16 = 32 MiB
#define ZX_OFF   51380224u           // 64 slots x [32][4096][4] bf16 = 64 MiB
#define WS_MAIN  118489088u

__device__ __forceinline__ unsigned short f2bf(float x) {
    union { float f; unsigned int u; } a; a.f = x;
    unsigned int r = a.u + 0x7fff + ((a.u >> 16) & 1);
    return (unsigned short)(r >> 16);
}

__device__ __forceinline__ float fsig(float x) {
    float e = __expf(-x);
    return __builtin_amdgcn_rcpf(1.0f + e);
}
__device__ __forceinline__ float ftanh(float x) {
    float e = __expf(2.0f * x);
    return 1.0f - 2.0f * __builtin_amdgcn_rcpf(e + 1.0f);
}

__device__ __forceinline__ void gll16(const void* g, void* l) {
    __builtin_amdgcn_global_load_lds(
        (const __attribute__((address_space(1))) unsigned int*)g,
        (__attribute__((address_space(3))) unsigned int*)l, 16, 0, 0);
}

// ---------------- phase 0 ----------------

__global__ __launch_bounds__(256) void cvt_wi(const float* __restrict__ Wf,
                                              const float* __restrict__ Wi,
                                              const float* __restrict__ Wg,
                                              const float* __restrict__ Wo,
                                              unsigned short* __restrict__ Wxi,
                                              unsigned short* __restrict__ Whi) {
    const int n = blockIdx.x;              // gate-col, n = hcol*4+gate
    const int k8 = threadIdx.x * 8;
    const int gate = n & 3, hcol = n >> 2;
    const float* src = ((gate == 0) ? Wf : (gate == 1) ? Wi : (gate == 2) ? Wg : Wo)
                       + (size_t)hcol * 2048 + k8;
    float4 a = *(const float4*)src;
    float4 b = *(const float4*)(src + 4);
    uint4 u;
    u.x = (unsigned)f2bf(a.x) | ((unsigned)f2bf(a.y) << 16);
    u.y = (unsigned)f2bf(a.z) | ((unsigned)f2bf(a.w) << 16);
    u.z = (unsigned)f2bf(b.x) | ((unsigned)f2bf(b.y) << 16);
    u.w = (unsigned)f2bf(b.z) | ((unsigned)f2bf(b.w) << 16);
    unsigned short* dst = (k8 < 1024) ? Wxi + (size_t)n * 1024 + k8
                                      : Whi + (size_t)n * 1024 + (k8 - 1024);
    *(uint4*)dst = u;
}

__global__ __launch_bounds__(256) void cvt_x(const float* __restrict__ X,
                                             unsigned short* __restrict__ dst) {
    size_t off = ((size_t)blockIdx.x * 256 + threadIdx.x) * 8;
    float4 a = *(const float4*)(X + off);
    float4 b = *(const float4*)(X + off + 4);
    uint4 u;
    u.x = (unsigned)f2bf(a.x) | ((unsigned)f2bf(a.y) << 16);
    u.y = (unsigned)f2bf(a.z) | ((unsigned)f2bf(a.w) << 16);
    u.z = (unsigned)f2bf(b.x) | ((unsigned)f2bf(b.y) << 16);
    u.w = (unsigned)f2bf(b.z) | ((unsigned)f2bf(b.w) << 16);
    *(uint4*)(dst + off) = u;
}

__global__ __launch_bounds__(256) void zero_ws(unsigned int* __restrict__ p) {
    p[blockIdx.x * 256 + threadIdx.x] = 0u;  // 1 MiB: h double-buffer + c
}

// ------- 128x128-tile Zx GEMM, 512 thr, 16-phase counted vmcnt -------------
// Grid 2048 (XCD-swizzled): mt = swz>>5 (one step), nt = swz&31.
// 8 waves 4Mx2N, wave tile 32x64 = acc[2][4]. BK=64, 16 chunks.
// LDS dynamic 128KB: A 4x16KB @0, B 4x16KB @65536. 4 glls/wave/stage,
// depth-3 -> waits 8..8,8,4,0 (prologue 12; wait 8 retires oldest stage).

__global__ __launch_bounds__(512) void gemm_zx128(
    const unsigned short* __restrict__ Xb,   // [64*128][1024] bf16 (chunk)
    const unsigned short* __restrict__ Wxi,  // [4096][1024] bf16
    unsigned short* __restrict__ Zc) {       // [64][32][4096][4] bf16
    extern __shared__ __align__(16) unsigned char smem[];

    const int tid = threadIdx.x;
    const int l = tid & 63;
    const int w = tid >> 6;              // 0..7
    const int wm = w >> 1, wn = w & 1;
    const int swz = (int)((blockIdx.x & 7) * 256 + (blockIdx.x >> 3));
    const int mt = swz >> 5;
    const int nt = swz & 31;
    const int lq = l >> 4, sp = l & 15;

    // staging: 1 gll = 1KB = 8 rows of 128B. A: wave w rows 16w..16w+15
    // (2 glls); B same on Wxi rows. lane l -> row +(l>>3), slot (l&7)^(row&7).
    const unsigned short* As[2];
    const unsigned short* Bs[2];
    unsigned adst[2], bdst[2];
#pragma unroll
    for (int q = 0; q < 2; ++q) {
        const int row = 16 * w + 8 * q + (l >> 3);
        const unsigned so = (unsigned)(((l & 7) ^ (row & 7)) * 8);
        As[q] = Xb + (size_t)(mt * 128 + row) * 1024 + so;
        Bs[q] = Wxi + (size_t)(nt * 128 + row) * 1024 + so;
        adst[q] = (unsigned)((16 * w + 8 * q) * 128);
        bdst[q] = 65536u + adst[q];
    }

    auto stage = [&](int c, int buf) {   // 4 glls/wave
        unsigned char* Ab = smem + buf * 16384;
        unsigned char* Bb = smem + buf * 16384;  // bdst includes +65536
#pragma unroll
        for (int q = 0; q < 2; ++q) {
            gll16(As[q] + c * 64, Ab + adst[q]);
            gll16(Bs[q] + c * 64, Bb + bdst[q]);
        }
    };

    f32x4 acc[2][4];
#pragma unroll
    for (int m = 0; m < 2; ++m)
#pragma unroll
        for (int n = 0; n < 4; ++n) acc[m][n] = {0.f, 0.f, 0.f, 0.f};

    auto compute = [&](int buf) {
        const unsigned char* Ab = smem + buf * 16384;
        const unsigned char* Bb = smem + 65536 + buf * 16384;
        short8 af[2][2], bfr[4][2];
#pragma unroll
        for (int m = 0; m < 2; ++m) {
            const int ar = wm * 32 + m * 16 + sp;
            const unsigned abase = (unsigned)(ar * 128), axor = (unsigned)((ar & 7) << 4);
#pragma unroll
            for (int k2 = 0; k2 < 2; ++k2)
                af[m][k2] = *(const short8*)(Ab + abase +
                            (((unsigned)(k2 * 64 + lq * 16)) ^ axor));
        }
#pragma unroll
        for (int n = 0; n < 4; ++n) {
            const int br = wn * 64 + n * 16 + sp;
            const unsigned bbase = (unsigned)(br * 128), bxor = (unsigned)((br & 7) << 4);
#pragma unroll
            for (int k2 = 0; k2 < 2; ++k2)
                bfr[n][k2] = *(const short8*)(Bb + bbase +
                             (((unsigned)(k2 * 64 + lq * 16)) ^ bxor));
        }
#pragma unroll
        for (int m = 0; m < 2; ++m)
#pragma unroll
            for (int n = 0; n < 4; ++n) {
                acc[m][n] = __builtin_amdgcn_mfma_f32_16x16x32_bf16(
                    af[m][0], bfr[n][0], acc[m][n], 0, 0, 0);
                acc[m][n] = __builtin_amdgcn_mfma_f32_16x16x32_bf16(
                    af[m][1], bfr[n][1], acc[m][n], 0, 0, 0);
            }
    };

    stage(0, 0); stage(1, 1); stage(2, 2);

#define GPH(c, WN, DO_STAGE)                                                  \
    asm volatile("s_waitcnt vmcnt(" #WN ") lgkmcnt(0)" ::: "memory");         \
    __builtin_amdgcn_sched_barrier(0);                                        \
    __builtin_amdgcn_s_barrier();                                             \
    if (DO_STAGE) stage((c) + 3, ((c) + 3) & 3);                              \
    compute((c) & 3);

    GPH(0, 8, 1)  GPH(1, 8, 1)  GPH(2, 8, 1)  GPH(3, 8, 1)
    GPH(4, 8, 1)  GPH(5, 8, 1)  GPH(6, 8, 1)  GPH(7, 8, 1)
    GPH(8, 8, 1)  GPH(9, 8, 1)  GPH(10, 8, 1) GPH(11, 8, 1)
    GPH(12, 8, 1) GPH(13, 8, 0) GPH(14, 4, 0) GPH(15, 0, 0)
#undef GPH

    // blocked bf16 store
#pragma unroll
    for (int m = 0; m < 2; ++m) {
        const int ri = wm * 32 + m * 16 + lq * 4;   // row within step (mt)
#pragma unroll
        for (int n = 0; n < 4; ++n) {
            const int ncol = nt * 128 + wn * 64 + n * 16 + sp;
            f32x4 z4 = acc[m][n];
            uint2 z2;
            z2.x = (unsigned)f2bf(z4[0]) | ((unsigned)f2bf(z4[1]) << 16);
            z2.y = (unsigned)f2bf(z4[2]) | ((unsigned)f2bf(z4[3]) << 16);
            *(uint2*)(Zc + (size_t)mt * 524288 + (size_t)(ri >> 2) * 16384 +
                      (size_t)ncol * 4) = z2;
        }
    }
}

// ------- per-timestep h-GEMM: BK=256, 4 phases, 3 bufs depth-2 -------------
// grid 256: rg = bid>>7 (0..1, 64 rows), cg = bid&127 (32 gate-cols).
// 512 thr / 8 waves: wm = w>>1 (16-row strip), wn = w&1 (16-col strip).
// LDS dynamic 144KB: A 3x32KB @0, B 3x16KB @98304. 6 glls/wave/stage
// (A 4, B 2), depth-2 -> waits 6,6,6,0. WAR: stage s3->b0 at PH1 is safe
// (all waves drained their b0 ds_reads via lgkmcnt(0) before barrier_1).

__global__ __launch_bounds__(512) void lstm_step6(
    const unsigned short* __restrict__ Zslot,   // [32][4096][4] bf16 blocked
    const unsigned short* __restrict__ Whi,     // [4096][1024] bf16
    const float* __restrict__ bfp, const float* __restrict__ bip,
    const float* __restrict__ bgp, const float* __restrict__ bop,
    const unsigned short* __restrict__ h_prev,  // [128][1024] bf16
    unsigned short* __restrict__ h_next,        // [128][1024] bf16
    float* __restrict__ c_ws,                   // [32][1024][4] f32 blocked
    float* __restrict__ out, int t) {
    extern __shared__ __align__(16) unsigned char smem[];

    const int tid = threadIdx.x;
    const int l = tid & 63;
    const int w = tid >> 6;              // 0..7
    const int wm = w >> 1, wn = w & 1;
    const int rg = blockIdx.x >> 7;      // 0..1
    const int cg = blockIdx.x & 127;
    const int lq = l >> 4, sp = l & 15;
    const int g0 = l & 3;
    const int n = cg * 32 + wn * 16 + sp;
    const int j = n >> 2;
    const int j0 = cg * 8 + wn * 4;
    const int cidx = sp >> 2;
    const int srcb = l & 48;
    const int rbase = rg * 64 + wm * 16 + lq * 4;

    // preloads (3 VMEM/thread; accounted in wait derivation)
    const float* bp = (g0 == 0) ? bfp : (g0 == 1) ? bip : (g0 == 2) ? bgp : bop;
    const float biasv = bp[j];
    uint2 zu = *(const uint2*)(Zslot + ((size_t)(rbase >> 2) * 4096 + n) * 4);
    float4 cp4 = *(const float4*)(c_ws + ((size_t)(rbase >> 2) * 1024 + j) * 4);

    f32x4 acc_a = {0.f, 0.f, 0.f, 0.f};
    f32x4 acc_b = {0.f, 0.f, 0.f, 0.f};

    // A staging: 64 rows x 512B; wave w rows 8w..8w+7 = 4 glls of 2 rows.
    // lane l: row +(l>>5), slot (l&31)^(row&7).
    const unsigned short* As[4];
    unsigned adst[4];
#pragma unroll
    for (int q = 0; q < 4; ++q) {
        const int row = 8 * w + 2 * q + (l >> 5);
        const unsigned so = (unsigned)(((l & 31) ^ (row & 7)) * 8);
        As[q] = h_prev + (size_t)(rg * 64 + row) * 1024 + so;
        adst[q] = (unsigned)((8 * w + 2 * q) * 512);
    }
    // B staging: 32 rows x 512B; wave w rows 4w..4w+3 = 2 glls of 2 rows.
    const unsigned short* Bs[2];
    unsigned bdst[2];
#pragma unroll
    for (int e = 0; e < 2; ++e) {
        const int row = 4 * w + 2 * e + (l >> 5);
        const unsigned so = (unsigned)(((l & 31) ^ (row & 7)) * 8);
        Bs[e] = Whi + (size_t)(cg * 32 + row) * 1024 + so;
        bdst[e] = (unsigned)(98304 + (4 * w + 2 * e) * 512);
    }

    auto stage = [&](int c, int buf) {  // 6 glls/wave
        unsigned char* Ab = smem + buf * 32768;
        unsigned char* Bb = smem + buf * 16384;  // bdst includes +98304
#pragma unroll
        for (int q = 0; q < 4; ++q) gll16(As[q] + c * 256, Ab + adst[q]);
#pragma unroll
        for (int e = 0; e < 2; ++e) gll16(Bs[e] + c * 256, Bb + bdst[e]);
    };
    auto compute = [&](int buf) {
        const unsigned char* Ab = smem + buf * 32768;
        const unsigned char* Bb = smem + 98304 + buf * 16384;
        const int ar = wm * 16 + sp;
        const int br = wn * 16 + sp;
        const unsigned abase = (unsigned)(ar * 512), axor = (unsigned)((ar & 7) << 4);
        const unsigned bbase = (unsigned)(br * 512), bxor = (unsigned)((br & 7) << 4);
#pragma unroll
        for (int ks = 0; ks < 8; ++ks) {
            const unsigned kk2 = (unsigned)(ks * 64 + lq * 16);
            short8 a = *(const short8*)(Ab + abase + (kk2 ^ axor));
            short8 b = *(const short8*)(Bb + bbase + (kk2 ^ bxor));
            if (ks & 1) acc_b = __builtin_amdgcn_mfma_f32_16x16x32_bf16(a, b, acc_b, 0, 0, 0);
            else        acc_a = __builtin_amdgcn_mfma_f32_16x16x32_bf16(a, b, acc_a, 0, 0, 0);
        }
    };

    stage(0, 0); stage(1, 1);
    // waits: PH0 entry = 3 preloads + 12 glls; vmcnt(6) retires preloads+s0.
    // PH1: s1,s2 out (12) -> 6 retires s1. PH2: s2,s3 (12) -> 6. PH3: 0.
#define SPH(c, WN, DO_STAGE, SBUF)                                            \
    asm volatile("s_waitcnt vmcnt(" #WN ") lgkmcnt(0)" ::: "memory");         \
    __builtin_amdgcn_sched_barrier(0);                                        \
    __builtin_amdgcn_s_barrier();                                             \
    if (DO_STAGE) stage((c) + 2, SBUF);                                       \
    compute((c) % 3);

    SPH(0, 6, 1, 2)
    SPH(1, 6, 1, 0)
    SPH(2, 6, 0, 0)
    SPH(3, 0, 0, 0)
#undef SPH

    // epilogue: z = zh + zx + bias (identical to R13)
    f32x4 z4 = acc_a + acc_b;
    z4[0] += __uint_as_float(zu.x << 16) + biasv;
    z4[1] += __uint_as_float(zu.x & 0xffff0000u) + biasv;
    z4[2] += __uint_as_float(zu.y << 16) + biasv;
    z4[3] += __uint_as_float(zu.y & 0xffff0000u) + biasv;
    float cpv[4] = {cp4.x, cp4.y, cp4.z, cp4.w};
    float hhv[4], ccv[4];
#pragma unroll
    for (int r = 0; r < 4; ++r) {
        float z = z4[r];
        float v1 = __shfl_xor(z, 1);
        float v2 = __shfl_xor(z, 2);
        float v3 = __shfl_xor(z, 3);
        float fg = fsig(z);
        float ig = fsig(v1);
        float gg = ftanh(v2);
        float og = fsig(v3);
        float cc = fg * cpv[r] + ig * gg;   // meaningful in g0==0 lanes
        ccv[r] = cc;
        hhv[r] = og * ftanh(cc);
    }
    if (g0 == 0) {
        float4 q4; q4.x = ccv[0]; q4.y = ccv[1]; q4.z = ccv[2]; q4.w = ccv[3];
        *(float4*)(c_ws + ((size_t)(rbase >> 2) * 1024 + j) * 4) = q4;
    }
#pragma unroll
    for (int r = 0; r < 4; ++r) {
        float e0 = __shfl(hhv[r], srcb + 0);
        float e1 = __shfl(hhv[r], srcb + 4);
        float e2 = __shfl(hhv[r], srcb + 8);
        float e3 = __shfl(hhv[r], srcb + 12);
        if (g0 == 0 && cidx == r) {
            const int row = rbase + r;
            float4 o4; o4.x = e0; o4.y = e1; o4.z = e2; o4.w = e3;
            *(float4*)(&out[((size_t)t * BB + row) * 1024 + j0]) = o4;
            uint2 h2;
            h2.x = (unsigned)f2bf(e0) | ((unsigned)f2bf(e1) << 16);
            h2.y = (unsigned)f2bf(e2) | ((unsigned)f2bf(e3) << 16);
            *(uint2*)(&h_next[(size_t)row * 1024 + j0]) = h2;
        }
        if (t == TT - 1) {
            float d0 = __shfl(ccv[r], srcb + 0);
            float d1 = __shfl(ccv[r], srcb + 4);
            float d2 = __shfl(ccv[r], srcb + 8);
            float d3 = __shfl(ccv[r], srcb + 12);
            if (g0 == 0 && cidx == r) {
                const int row = rbase + r;
                float4 o4; o4.x = e0; o4.y = e1; o4.z = e2; o4.w = e3;
                float4 q4; q4.x = d0; q4.y = d1; q4.z = d2; q4.w = d3;
                *(float4*)(&out[(size_t)TT * BB * 1024 + (size_t)row * 1024 + j0]) = o4;
                *(float4*)(&out[(size_t)TT * BB * 1024 + (size_t)BB * 1024 +
                                (size_t)row * 1024 + j0]) = q4;
            }
        }
    }
}

// ---------------- fallback 32x32-tile Zx body (R9-proven) ----------------

__device__ __forceinline__ void gemm_tile_body(
    const float* __restrict__ Xt, const unsigned short* __restrict__ Wxi,
    unsigned short* __restrict__ Zslot, int mt, int cg, unsigned char* smem) {
    const int tid = threadIdx.x;
    const int l = tid & 63;
    const int w = tid >> 6;
    const int wr = w >> 1, wc = w & 1;
    const int lq = l >> 4, sp = l & 15;

    f32x4 acc_a = {0.f, 0.f, 0.f, 0.f};
    f32x4 acc_b = {0.f, 0.f, 0.f, 0.f};

    const int xrow = tid >> 3;
    const int xs = (tid & 7) * 2;
    const float* xsrc = Xt + (size_t)(mt * 32 + xrow) * 1024 + xs * 8;
    const unsigned xw0 = (unsigned)(xrow * 256 + ((xs * 16) ^ ((xrow & 7) << 4)));
    const unsigned xw1 = (unsigned)(xrow * 256 + (((xs + 1) * 16) ^ ((xrow & 7) << 4)));
    float4 xv0, xv1, xv2, xv3;

    const int bn0 = w * 8 + lq, bn1 = bn0 + 4;
    const unsigned short* wsrc0 = Wxi + (size_t)(cg * 32 + bn0) * 1024 + (sp ^ (bn0 & 7)) * 8;
    const unsigned short* wsrc1 = Wxi + (size_t)(cg * 32 + bn1) * 1024 + (sp ^ (bn1 & 7)) * 8;

    auto load_x = [&](int c) {
        const float* p = xsrc + c * 128;
        xv0 = *(const float4*)(p);     xv1 = *(const float4*)(p + 4);
        xv2 = *(const float4*)(p + 8); xv3 = *(const float4*)(p + 12);
    };
    auto write_x = [&](int buf) {
        unsigned char* Ab = smem + (buf ? 8192 : 0);
        uint4 u0, u1;
        u0.x = (unsigned)f2bf(xv0.x) | ((unsigned)f2bf(xv0.y) << 16);
        u0.y = (unsigned)f2bf(xv0.z) | ((unsigned)f2bf(xv0.w) << 16);
        u0.z = (unsigned)f2bf(xv1.x) | ((unsigned)f2bf(xv1.y) << 16);
        u0.w = (unsigned)f2bf(xv1.z) | ((unsigned)f2bf(xv1.w) << 16);
        u1.x = (unsigned)f2bf(xv2.x) | ((unsigned)f2bf(xv2.y) << 16);
        u1.y = (unsigned)f2bf(xv2.z) | ((unsigned)f2bf(xv2.w) << 16);
        u1.z = (unsigned)f2bf(xv3.x) | ((unsigned)f2bf(xv3.y) << 16);
        u1.w = (unsigned)f2bf(xv3.z) | ((unsigned)f2bf(xv3.w) << 16);
        *(uint4*)(Ab + xw0) = u0; *(uint4*)(Ab + xw1) = u1;
    };
    auto stage_B = [&](int c, int buf) {
        unsigned char* Bb = smem + 16384 + (buf ? 8192 : 0);
        gll16(wsrc0 + c * 128, Bb + (w * 8) * 256);
        gll16(wsrc1 + c * 128, Bb + (w * 8 + 4) * 256);
    };
    auto compute = [&](int buf) {
        const unsigned char* Ab = smem + (buf ? 8192 : 0);
        const unsigned char* Bb = smem + 16384 + (buf ? 8192 : 0);
        const int ar = wr * 16 + sp;
        const int br = wc * 16 + sp;
        const unsigned abase = (unsigned)(ar * 256), axor = (unsigned)((ar & 7) << 4);
        const unsigned bbase = (unsigned)(br * 256), bxor = (unsigned)((br & 7) << 4);
#pragma unroll
        for (int ks = 0; ks < 4; ++ks) {
            const unsigned kk2 = (unsigned)((ks * 4 + lq) << 4);
            short8 a = *(const short8*)(Ab + abase + (kk2 ^ axor));
            short8 b = *(const short8*)(Bb + bbase + (kk2 ^ bxor));
            if (ks & 1) acc_b = __builtin_amdgcn_mfma_f32_16x16x32_bf16(a, b, acc_b, 0, 0, 0);
            else        acc_a = __builtin_amdgcn_mfma_f32_16x16x32_bf16(a, b, acc_a, 0, 0, 0);
        }
    };

    load_x(0); stage_B(0, 0); write_x(0);
    __syncthreads();
    for (int c = 0; c < 8; ++c) {
        const int buf = c & 1, nbuf = buf ^ 1;
        if (c < 7) { load_x(c + 1); stage_B(c + 1, nbuf); }
        compute(buf);
        if (c < 7) write_x(nbuf);
        __syncthreads();
    }

    const int rowb = mt * 32 + wr * 16 + lq * 4;
    const int n = cg * 32 + wc * 16 + sp;
    f32x4 z4 = acc_a + acc_b;
    uint2 z2;
    z2.x = (unsigned)f2bf(z4[0]) | ((unsigned)f2bf(z4[1]) << 16);
    z2.y = (unsigned)f2bf(z4[2]) | ((unsigned)f2bf(z4[3]) << 16);
    *(uint2*)(Zslot + ((size_t)(rowb >> 2) * 4096 + n) * 4) = z2;
}

__global__ __launch_bounds__(256) void gemm_zx32(
    const float* __restrict__ X, const unsigned short* __restrict__ Wxi,
    unsigned short* __restrict__ Zring) {
    __shared__ __align__(16) unsigned char smem[32768];
    const int tl = blockIdx.x >> 9;
    const int inner = blockIdx.x & 511;
    gemm_tile_body(X + (size_t)tl * 131072, Wxi, Zring + (size_t)tl * 524288,
                   inner >> 7, inner & 127, smem);
}

// ---------------- host ----------------

extern "C" void kernel_launch(void* const* d_in, const int* in_sizes, int n_in,
                              void* d_out, int out_size, void* d_ws, size_t ws_size,
                              hipStream_t stream) {
    const float* X  = (const float*)d_in[0];
    const float* Wf = (const float*)d_in[1];
    const float* bf = (const float*)d_in[2];
    const float* Wi = (const float*)d_in[3];
    const float* bi = (const float*)d_in[4];
    const float* Wg = (const float*)d_in[5];
    const float* bg = (const float*)d_in[6];
    const float* Wo = (const float*)d_in[7];
    const float* bo = (const float*)d_in[8];
    unsigned char* ws = (unsigned char*)d_ws;

    unsigned short* Wxi = (unsigned short*)(ws + WX_OFF);
    unsigned short* Whi = (unsigned short*)(ws + WH_OFF);
    unsigned short* hbuf = (unsigned short*)(ws + H_OFF);
    float* c_ws = (float*)(ws + C_OFF);
    float* outp = (float*)d_out;

    cvt_wi<<<dim3(4096), dim3(256), 0, stream>>>(Wf, Wi, Wg, Wo, Wxi, Whi);
    zero_ws<<<dim3(1024), dim3(256), 0, stream>>>((unsigned int*)(ws + H_OFF));
    hipFuncSetAttribute((const void*)lstm_step6,
                        hipFuncAttributeMaxDynamicSharedMemorySize, 147456);
    hipFuncSetAttribute((const void*)gemm_zx128,
                        hipFuncAttributeMaxDynamicSharedMemorySize, 131072);

    if (ws_size >= WS_MAIN) {
        unsigned short* Xb = (unsigned short*)(ws + XBF_OFF);
        unsigned short* Zx = (unsigned short*)(ws + ZX_OFF);
        for (int q = 0; q < 4; ++q) {
            cvt_x<<<dim3(8192), dim3(256), 0, stream>>>(
                X + (size_t)q * 16777216, Xb);
            for (int c2 = 0; c2 < 2; ++c2) {          // 2 chunks of 64 steps
                gemm_zx128<<<dim3(2048), dim3(512), 131072, stream>>>(
                    Xb + (size_t)c2 * 8388608, Wxi, Zx);
                for (int tl = 0; tl < 64; ++tl) {
                    const int t = q * 128 + c2 * 64 + tl;
                    const unsigned short* hp = hbuf + (size_t)(t & 1) * (BB * 1024);
                    unsigned short* hn = hbuf + (size_t)((t + 1) & 1) * (BB * 1024);
                    lstm_step6<<<dim3(256), dim3(512), 147456, stream>>>(
                        Zx + (size_t)tl * 524288, Whi, bf, bi, bg, bo,
                        hp, hn, c_ws, outp, t);
                }
            }
        }
    } else {
        unsigned short* Zx = (unsigned short*)(ws + XBF_OFF);
        int C = 4;
        const int cands[4] = {64, 16, 8, 4};
        for (int i = 0; i < 4; ++i) {
            if ((size_t)XBF_OFF + (size_t)cands[i] * 1048576u <= ws_size) { C = cands[i]; break; }
        }
        const int nchunks = TT / C;
        for (int ch = 0; ch < nchunks; ++ch) {
            gemm_zx32<<<dim3(C * 512), dim3(256), 0, stream>>>(
                X + (size_t)ch * C * 131072, Wxi, Zx);
            for (int tl = 0; tl < C; ++tl) {
                const int t = ch * C + tl;
                const unsigned short* hp = hbuf + (size_t)(t & 1) * (BB * 1024);
                unsigned short* hn = hbuf + (size_t)((t + 1) & 1) * (BB * 1024);
                lstm_step6<<<dim3(256), dim3(512), 147456, stream>>>(
                    Zx + (size_t)tl * 524288, Whi, bf, bi, bg, bo,
                    hp, hn, c_ws, outp, t);
            }
        }
    }
}

// Round 15
// 4256.231 us; speedup vs baseline: 1.0311x; 1.0311x over previous
//
#include <hip/hip_runtime.h>

// LSTM T=512,B=128,D=H=1024. R15 = R13 verbatim with ONE change:
// gemm_zx128 converted to 3-buffer depth-2 counted-vmcnt (waits 8x15,0) +
// XCD-bijective block swizzle. Step kernel = R13's proven lstm_step5.
// Gate interleave: n = hcol*4+gate -> f/i/g/o in lanes l^{0,1,2,3}.

#define TT 512
#define BB 128

typedef __attribute__((ext_vector_type(8))) short short8;
typedef __attribute__((ext_vector_type(4))) float f32x4;

// ws layout (main tier) — bound proven by R11/R13 passing runs
#define WX_OFF   0u                  // [4096][1024] bf16 = 8 MiB
#define WH_OFF   8388608u            // [4096][1024] bf16 = 8 MiB
#define H_OFF    16777216u           // 2 x [128][1024] bf16 = 512 KiB
#define C_OFF    17301504u           // [32][1024][4] f32 = 512 KiB (blocked)
#define XBF_OFF  17825792u           // quarter X: [128*128][1024] bf16 = 32 MiB
#define ZX_OFF   51380224u           // 64 slots x [32][4096][4] bf16 = 64 MiB
#define WS_MAIN  118489088u

__device__ __forceinline__ unsigned short f2bf(float x) {
    union { float f; unsigned int u; } a; a.f = x;
    unsigned int r = a.u + 0x7fff + ((a.u >> 16) & 1);
    return (unsigned short)(r >> 16);
}

__device__ __forceinline__ float fsig(float x) {
    float e = __expf(-x);
    return __builtin_amdgcn_rcpf(1.0f + e);
}
__device__ __forceinline__ float ftanh(float x) {
    float e = __expf(2.0f * x);
    return 1.0f - 2.0f * __builtin_amdgcn_rcpf(e + 1.0f);
}

__device__ __forceinline__ void gll16(const void* g, void* l) {
    __builtin_amdgcn_global_load_lds(
        (const __attribute__((address_space(1))) unsigned int*)g,
        (__attribute__((address_space(3))) unsigned int*)l, 16, 0, 0);
}

// ---------------- phase 0 ----------------

__global__ __launch_bounds__(256) void cvt_wi(const float* __restrict__ Wf,
                                              const float* __restrict__ Wi,
                                              const float* __restrict__ Wg,
                                              const float* __restrict__ Wo,
                                              unsigned short* __restrict__ Wxi,
                                              unsigned short* __restrict__ Whi) {
    const int n = blockIdx.x;              // gate-col, n = hcol*4+gate
    const int k8 = threadIdx.x * 8;
    const int gate = n & 3, hcol = n >> 2;
    const float* src = ((gate == 0) ? Wf : (gate == 1) ? Wi : (gate == 2) ? Wg : Wo)
                       + (size_t)hcol * 2048 + k8;
    float4 a = *(const float4*)src;
    float4 b = *(const float4*)(src + 4);
    uint4 u;
    u.x = (unsigned)f2bf(a.x) | ((unsigned)f2bf(a.y) << 16);
    u.y = (unsigned)f2bf(a.z) | ((unsigned)f2bf(a.w) << 16);
    u.z = (unsigned)f2bf(b.x) | ((unsigned)f2bf(b.y) << 16);
    u.w = (unsigned)f2bf(b.z) | ((unsigned)f2bf(b.w) << 16);
    unsigned short* dst = (k8 < 1024) ? Wxi + (size_t)n * 1024 + k8
                                      : Whi + (size_t)n * 1024 + (k8 - 1024);
    *(uint4*)dst = u;
}

__global__ __launch_bounds__(256) void cvt_x(const float* __restrict__ X,
                                             unsigned short* __restrict__ dst) {
    size_t off = ((size_t)blockIdx.x * 256 + threadIdx.x) * 8;
    float4 a = *(const float4*)(X + off);
    float4 b = *(const float4*)(X + off + 4);
    uint4 u;
    u.x = (unsigned)f2bf(a.x) | ((unsigned)f2bf(a.y) << 16);
    u.y = (unsigned)f2bf(a.z) | ((unsigned)f2bf(a.w) << 16);
    u.z = (unsigned)f2bf(b.x) | ((unsigned)f2bf(b.y) << 16);
    u.w = (unsigned)f2bf(b.z) | ((unsigned)f2bf(b.w) << 16);
    *(uint4*)(dst + off) = u;
}

__global__ __launch_bounds__(256) void zero_ws(unsigned int* __restrict__ p) {
    p[blockIdx.x * 256 + threadIdx.x] = 0u;  // 1 MiB: h double-buffer + c
}

// ------- 128x128-tile Zx GEMM: R13 structure + 3-buf counted vmcnt ---------
// Grid 2048 (XCD-bijective swizzle): mt = swz>>5 (one step), nt = swz&31.
// 256 thr / 4 waves (2x2), wave tile 64x64 = 4x4 frags. BK=64, 16 chunks.
// LDS dynamic 96KB: A 3x16KB @0, B 3x16KB @49152. 8 glls/wave/stage,
// depth-2 -> waits: 8 at PH0..PH14 (retires exactly the oldest stage), 0 at
// PH15. WAR: stage(c+2) overwrites buf((c-1)%3); its readers drained their
// ds_reads via lgkmcnt(0) before the barrier all waves pass first.

__global__ __launch_bounds__(256) void gemm_zx128(
    const unsigned short* __restrict__ Xb,   // [64*128][1024] bf16 (chunk)
    const unsigned short* __restrict__ Wxi,  // [4096][1024] bf16
    unsigned short* __restrict__ Zc) {       // [64][32][4096][4] bf16
    extern __shared__ __align__(16) unsigned char smem[];

    const int tid = threadIdx.x;
    const int l = tid & 63;
    const int w = tid >> 6;
    const int wr = w >> 1, wc = w & 1;
    const int swz = (int)((blockIdx.x & 7) * 256 + (blockIdx.x >> 3));
    const int mt = swz >> 5;
    const int nt = swz & 31;
    const int lq = l >> 4, sp = l & 15;

    // staging (R13-proven mapping): seg = w*4+q covers 8 rows x 128 B;
    // lane l -> row seg*8+(l>>3), slot (l&7)^(row&7); LDS dest wave-uniform.
    const int srow = l >> 3;
    const int sslot = l & 7;
    const unsigned short* As[4];
    const unsigned short* Bs[4];
    unsigned dstb[4];
#pragma unroll
    for (int q = 0; q < 4; ++q) {
        const int seg = w * 4 + q;
        const int row = seg * 8 + srow;
        const unsigned so = (unsigned)((sslot ^ (row & 7)) * 8);
        As[q] = Xb + (size_t)(mt * 128 + row) * 1024 + so;
        Bs[q] = Wxi + (size_t)(nt * 128 + row) * 1024 + so;
        dstb[q] = (unsigned)(seg * 1024);     // wave-uniform; HW adds lane*16
    }

    auto stage = [&](int c, int buf) {   // 8 glls/wave
        unsigned char* Ab = smem + buf * 16384;
        unsigned char* Bb = smem + 49152 + buf * 16384;
#pragma unroll
        for (int q = 0; q < 4; ++q) {
            gll16(As[q] + c * 64, Ab + dstb[q]);
            gll16(Bs[q] + c * 64, Bb + dstb[q]);
        }
    };

    f32x4 acc[4][4];
#pragma unroll
    for (int m = 0; m < 4; ++m)
#pragma unroll
        for (int n = 0; n < 4; ++n) acc[m][n] = {0.f, 0.f, 0.f, 0.f};

    auto compute = [&](int buf) {        // R13-proven compute mapping
        const unsigned char* Ab = smem + buf * 16384;
        const unsigned char* Bb = smem + 49152 + buf * 16384;
        short8 af[4][2], bfr[4][2];
#pragma unroll
        for (int m = 0; m < 4; ++m) {
            const int ar = wr * 64 + m * 16 + sp;
            const unsigned abase = (unsigned)(ar * 128), axor = (unsigned)((ar & 7) << 4);
#pragma unroll
            for (int k2 = 0; k2 < 2; ++k2)
                af[m][k2] = *(const short8*)(Ab + abase +
                            (((unsigned)(k2 * 64 + lq * 16)) ^ axor));
        }
#pragma unroll
        for (int n = 0; n < 4; ++n) {
            const int br = wc * 64 + n * 16 + sp;
            const unsigned bbase = (unsigned)(br * 128), bxor = (unsigned)((br & 7) << 4);
#pragma unroll
            for (int k2 = 0; k2 < 2; ++k2)
                bfr[n][k2] = *(const short8*)(Bb + bbase +
                             (((unsigned)(k2 * 64 + lq * 16)) ^ bxor));
        }
#pragma unroll
        for (int m = 0; m < 4; ++m)
#pragma unroll
            for (int n = 0; n < 4; ++n) {
                acc[m][n] = __builtin_amdgcn_mfma_f32_16x16x32_bf16(
                    af[m][0], bfr[n][0], acc[m][n], 0, 0, 0);
                acc[m][n] = __builtin_amdgcn_mfma_f32_16x16x32_bf16(
                    af[m][1], bfr[n][1], acc[m][n], 0, 0, 0);
            }
    };

    stage(0, 0); stage(1, 1);

#define GPH(c, WN, DO_STAGE)                                                  \
    asm volatile("s_waitcnt vmcnt(" #WN ") lgkmcnt(0)" ::: "memory");         \
    __builtin_amdgcn_sched_barrier(0);                                        \
    __builtin_amdgcn_s_barrier();                                             \
    if (DO_STAGE) stage((c) + 2, ((c) + 2) % 3);                              \
    compute((c) % 3);

    GPH(0, 8, 1)  GPH(1, 8, 1)  GPH(2, 8, 1)  GPH(3, 8, 1)
    GPH(4, 8, 1)  GPH(5, 8, 1)  GPH(6, 8, 1)  GPH(7, 8, 1)
    GPH(8, 8, 1)  GPH(9, 8, 1)  GPH(10, 8, 1) GPH(11, 8, 1)
    GPH(12, 8, 1) GPH(13, 8, 1) GPH(14, 8, 0) GPH(15, 0, 0)
#undef GPH

    // blocked bf16 store (R13-proven)
#pragma unroll
    for (int m = 0; m < 4; ++m) {
        const int ri = wr * 64 + m * 16 + lq * 4;   // row within step (mt)
#pragma unroll
        for (int n = 0; n < 4; ++n) {
            const int ncol = nt * 128 + wc * 64 + n * 16 + sp;
            f32x4 z4 = acc[m][n];
            uint2 z2;
            z2.x = (unsigned)f2bf(z4[0]) | ((unsigned)f2bf(z4[1]) << 16);
            z2.y = (unsigned)f2bf(z4[2]) | ((unsigned)f2bf(z4[3]) << 16);
            *(uint2*)(Zc + (size_t)mt * 524288 + (size_t)(ri >> 2) * 16384 +
                      (size_t)ncol * 4) = z2;
        }
    }
}

// ---------------- per-timestep h-GEMM (R13 verbatim) -----------------------
// grid 256: rg = bid>>7 (0..1, 64 rows), cg = bid&127 (32 gate-cols).
// 512 thr / 8 waves: wm = w>>1 (16-row strip), wn = w&1 (16-col strip).
// 8 K-chunks of 128; depth-3 counted vmcnt, 3 glls/wave/stage.
// LDS dynamic 96KB: A 4x16KB @0, B 4x8KB @65536. Waits 6,6,6,6,6,6,3,0.

__global__ __launch_bounds__(512) void lstm_step5(
    const unsigned short* __restrict__ Zslot,   // [32][4096][4] bf16 blocked
    const unsigned short* __restrict__ Whi,     // [4096][1024] bf16
    const float* __restrict__ bfp, const float* __restrict__ bip,
    const float* __restrict__ bgp, const float* __restrict__ bop,
    const unsigned short* __restrict__ h_prev,  // [128][1024] bf16
    unsigned short* __restrict__ h_next,        // [128][1024] bf16
    float* __restrict__ c_ws,                   // [32][1024][4] f32 blocked
    float* __restrict__ out, int t) {
    extern __shared__ __align__(16) unsigned char smem[];

    const int tid = threadIdx.x;
    const int l = tid & 63;
    const int w = tid >> 6;              // 0..7
    const int wm = w >> 1, wn = w & 1;
    const int rg = blockIdx.x >> 7;      // 0..1
    const int cg = blockIdx.x & 127;
    const int lq = l >> 4, sp = l & 15;
    const int g0 = l & 3;
    const int n = cg * 32 + wn * 16 + sp;
    const int j = n >> 2;
    const int j0 = cg * 8 + wn * 4;
    const int cidx = sp >> 2;
    const int srcb = l & 48;
    const int rbase = rg * 64 + wm * 16 + lq * 4;

    // preloads (3 VMEM/thread)
    const float* bp = (g0 == 0) ? bfp : (g0 == 1) ? bip : (g0 == 2) ? bgp : bop;
    const float biasv = bp[j];
    uint2 zu = *(const uint2*)(Zslot + ((size_t)(rbase >> 2) * 4096 + n) * 4);
    float4 cp4 = *(const float4*)(c_ws + ((size_t)(rbase >> 2) * 1024 + j) * 4);

    f32x4 acc_a = {0.f, 0.f, 0.f, 0.f};
    f32x4 acc_b = {0.f, 0.f, 0.f, 0.f};

    // A staging: 16 segs of 1KB (4 rows x 256B); wave w -> segs w*2, w*2+1.
    const int ar0 = (w * 2 + 0) * 4 + (l >> 4);
    const int ar1 = (w * 2 + 1) * 4 + (l >> 4);
    const unsigned short* hsrc0 =
        h_prev + (size_t)(rg * 64 + ar0) * 1024 + ((sp ^ (ar0 & 7)) * 8);
    const unsigned short* hsrc1 =
        h_prev + (size_t)(rg * 64 + ar1) * 1024 + ((sp ^ (ar1 & 7)) * 8);
    // B staging: 8 segs of 1KB; wave w -> seg w; brow = w*4 + (l>>4).
    const int brw = w * 4 + (l >> 4);
    const unsigned short* wsrc =
        Whi + (size_t)(cg * 32 + brw) * 1024 + ((sp ^ (brw & 7)) * 8);

    auto stage = [&](int c, int buf) {  // 3 glls/wave
        unsigned char* Ab = smem + buf * 16384;
        unsigned char* Bb = smem + 65536 + buf * 8192;
        gll16(hsrc0 + c * 128, Ab + (w * 2 + 0) * 1024);
        gll16(hsrc1 + c * 128, Ab + (w * 2 + 1) * 1024);
        gll16(wsrc + c * 128, Bb + w * 1024);
    };
    auto compute = [&](int buf) {
        const unsigned char* Ab = smem + buf * 16384;
        const unsigned char* Bb = smem + 65536 + buf * 8192;
        const int ar = wm * 16 + sp;
        const int br = wn * 16 + sp;
        const unsigned abase = (unsigned)(ar * 256), axor = (unsigned)((ar & 7) << 4);
        const unsigned bbase = (unsigned)(br * 256), bxor = (unsigned)((br & 7) << 4);
#pragma unroll
        for (int ks = 0; ks < 4; ++ks) {
            const unsigned kk2 = (unsigned)((ks * 4 + lq) << 4);
            short8 a = *(const short8*)(Ab + abase + (kk2 ^ axor));
            short8 b = *(const short8*)(Bb + bbase + (kk2 ^ bxor));
            if (ks & 1) acc_b = __builtin_amdgcn_mfma_f32_16x16x32_bf16(a, b, acc_b, 0, 0, 0);
            else        acc_a = __builtin_amdgcn_mfma_f32_16x16x32_bf16(a, b, acc_a, 0, 0, 0);
        }
    };

    stage(0, 0); stage(1, 1); stage(2, 2);

#define PH(c, WN, DO_STAGE)                                                   \
    asm volatile("s_waitcnt vmcnt(" #WN ") lgkmcnt(0)" ::: "memory");         \
    __builtin_amdgcn_sched_barrier(0);                                        \
    __builtin_amdgcn_s_barrier();                                             \
    if (DO_STAGE) stage((c) + 3, ((c) + 3) & 3);                              \
    compute((c) & 3);

    PH(0, 6, 1)
    PH(1, 6, 1)
    PH(2, 6, 1)
    PH(3, 6, 1)
    PH(4, 6, 1)
    PH(5, 6, 0)
    PH(6, 3, 0)
    PH(7, 0, 0)
#undef PH

    // epilogue: z = zh + zx + bias
    f32x4 z4 = acc_a + acc_b;
    z4[0] += __uint_as_float(zu.x << 16) + biasv;
    z4[1] += __uint_as_float(zu.x & 0xffff0000u) + biasv;
    z4[2] += __uint_as_float(zu.y << 16) + biasv;
    z4[3] += __uint_as_float(zu.y & 0xffff0000u) + biasv;
    float cpv[4] = {cp4.x, cp4.y, cp4.z, cp4.w};
    float hhv[4], ccv[4];
#pragma unroll
    for (int r = 0; r < 4; ++r) {
        float z = z4[r];
        float v1 = __shfl_xor(z, 1);
        float v2 = __shfl_xor(z, 2);
        float v3 = __shfl_xor(z, 3);
        float fg = fsig(z);
        float ig = fsig(v1);
        float gg = ftanh(v2);
        float og = fsig(v3);
        float cc = fg * cpv[r] + ig * gg;   // meaningful in g0==0 lanes
        ccv[r] = cc;
        hhv[r] = og * ftanh(cc);
    }
    if (g0 == 0) {  // blocked c store, no transpose
        float4 q4; q4.x = ccv[0]; q4.y = ccv[1]; q4.z = ccv[2]; q4.w = ccv[3];
        *(float4*)(c_ws + ((size_t)(rbase >> 2) * 1024 + j) * 4) = q4;
    }
#pragma unroll
    for (int r = 0; r < 4; ++r) {
        float e0 = __shfl(hhv[r], srcb + 0);
        float e1 = __shfl(hhv[r], srcb + 4);
        float e2 = __shfl(hhv[r], srcb + 8);
        float e3 = __shfl(hhv[r], srcb + 12);
        if (g0 == 0 && cidx == r) {
            const int row = rbase + r;
            float4 o4; o4.x = e0; o4.y = e1; o4.z = e2; o4.w = e3;
            *(float4*)(&out[((size_t)t * BB + row) * 1024 + j0]) = o4;
            uint2 h2;
            h2.x = (unsigned)f2bf(e0) | ((unsigned)f2bf(e1) << 16);
            h2.y = (unsigned)f2bf(e2) | ((unsigned)f2bf(e3) << 16);
            *(uint2*)(&h_next[(size_t)row * 1024 + j0]) = h2;
        }
        if (t == TT - 1) {
            float d0 = __shfl(ccv[r], srcb + 0);
            float d1 = __shfl(ccv[r], srcb + 4);
            float d2 = __shfl(ccv[r], srcb + 8);
            float d3 = __shfl(ccv[r], srcb + 12);
            if (g0 == 0 && cidx == r) {
                const int row = rbase + r;
                float4 o4; o4.x = e0; o4.y = e1; o4.z = e2; o4.w = e3;
                float4 q4; q4.x = d0; q4.y = d1; q4.z = d2; q4.w = d3;
                *(float4*)(&out[(size_t)TT * BB * 1024 + (size_t)row * 1024 + j0]) = o4;
                *(float4*)(&out[(size_t)TT * BB * 1024 + (size_t)BB * 1024 +
                                (size_t)row * 1024 + j0]) = q4;
            }
        }
    }
}

// ---------------- fallback 32x32-tile Zx body (R9-proven) ----------------

__device__ __forceinline__ void gemm_tile_body(
    const float* __restrict__ Xt, const unsigned short* __restrict__ Wxi,
    unsigned short* __restrict__ Zslot, int mt, int cg, unsigned char* smem) {
    const int tid = threadIdx.x;
    const int l = tid & 63;
    const int w = tid >> 6;
    const int wr = w >> 1, wc = w & 1;
    const int lq = l >> 4, sp = l & 15;

    f32x4 acc_a = {0.f, 0.f, 0.f, 0.f};
    f32x4 acc_b = {0.f, 0.f, 0.f, 0.f};

    const int xrow = tid >> 3;
    const int xs = (tid & 7) * 2;
    const float* xsrc = Xt + (size_t)(mt * 32 + xrow) * 1024 + xs * 8;
    const unsigned xw0 = (unsigned)(xrow * 256 + ((xs * 16) ^ ((xrow & 7) << 4)));
    const unsigned xw1 = (unsigned)(xrow * 256 + (((xs + 1) * 16) ^ ((xrow & 7) << 4)));
    float4 xv0, xv1, xv2, xv3;

    const int bn0 = w * 8 + lq, bn1 = bn0 + 4;
    const unsigned short* wsrc0 = Wxi + (size_t)(cg * 32 + bn0) * 1024 + (sp ^ (bn0 & 7)) * 8;
    const unsigned short* wsrc1 = Wxi + (size_t)(cg * 32 + bn1) * 1024 + (sp ^ (bn1 & 7)) * 8;

    auto load_x = [&](int c) {
        const float* p = xsrc + c * 128;
        xv0 = *(const float4*)(p);     xv1 = *(const float4*)(p + 4);
        xv2 = *(const float4*)(p + 8); xv3 = *(const float4*)(p + 12);
    };
    auto write_x = [&](int buf) {
        unsigned char* Ab = smem + (buf ? 8192 : 0);
        uint4 u0, u1;
        u0.x = (unsigned)f2bf(xv0.x) | ((unsigned)f2bf(xv0.y) << 16);
        u0.y = (unsigned)f2bf(xv0.z) | ((unsigned)f2bf(xv0.w) << 16);
        u0.z = (unsigned)f2bf(xv1.x) | ((unsigned)f2bf(xv1.y) << 16);
        u0.w = (unsigned)f2bf(xv1.z) | ((unsigned)f2bf(xv1.w) << 16);
        u1.x = (unsigned)f2bf(xv2.x) | ((unsigned)f2bf(xv2.y) << 16);
        u1.y = (unsigned)f2bf(xv2.z) | ((unsigned)f2bf(xv2.w) << 16);
        u1.z = (unsigned)f2bf(xv3.x) | ((unsigned)f2bf(xv3.y) << 16);
        u1.w = (unsigned)f2bf(xv3.z) | ((unsigned)f2bf(xv3.w) << 16);
        *(uint4*)(Ab + xw0) = u0; *(uint4*)(Ab + xw1) = u1;
    };
    auto stage_B = [&](int c, int buf) {
        unsigned char* Bb = smem + 16384 + (buf ? 8192 : 0);
        gll16(wsrc0 + c * 128, Bb + (w * 8) * 256);
        gll16(wsrc1 + c * 128, Bb + (w * 8 + 4) * 256);
    };
    auto compute = [&](int buf) {
        const unsigned char* Ab = smem + (buf ? 8192 : 0);
        const unsigned char* Bb = smem + 16384 + (buf ? 8192 : 0);
        const int ar = wr * 16 + sp;
        const int br = wc * 16 + sp;
        const unsigned abase = (unsigned)(ar * 256), axor = (unsigned)((ar & 7) << 4);
        const unsigned bbase = (unsigned)(br * 256), bxor = (unsigned)((br & 7) << 4);
#pragma unroll
        for (int ks = 0; ks < 4; ++ks) {
            const unsigned kk2 = (unsigned)((ks * 4 + lq) << 4);
            short8 a = *(const short8*)(Ab + abase + (kk2 ^ axor));
            short8 b = *(const short8*)(Bb + bbase + (kk2 ^ bxor));
            if (ks & 1) acc_b = __builtin_amdgcn_mfma_f32_16x16x32_bf16(a, b, acc_b, 0, 0, 0);
            else        acc_a = __builtin_amdgcn_mfma_f32_16x16x32_bf16(a, b, acc_a, 0, 0, 0);
        }
    };

    load_x(0); stage_B(0, 0); write_x(0);
    __syncthreads();
    for (int c = 0; c < 8; ++c) {
        const int buf = c & 1, nbuf = buf ^ 1;
        if (c < 7) { load_x(c + 1); stage_B(c + 1, nbuf); }
        compute(buf);
        if (c < 7) write_x(nbuf);
        __syncthreads();
    }

    const int rowb = mt * 32 + wr * 16 + lq * 4;
    const int n = cg * 32 + wc * 16 + sp;
    f32x4 z4 = acc_a + acc_b;
    uint2 z2;
    z2.x = (unsigned)f2bf(z4[0]) | ((unsigned)f2bf(z4[1]) << 16);
    z2.y = (unsigned)f2bf(z4[2]) | ((unsigned)f2bf(z4[3]) << 16);
    *(uint2*)(Zslot + ((size_t)(rowb >> 2) * 4096 + n) * 4) = z2;
}

__global__ __launch_bounds__(256) void gemm_zx32(
    const float* __restrict__ X, const unsigned short* __restrict__ Wxi,
    unsigned short* __restrict__ Zring) {
    __shared__ __align__(16) unsigned char smem[32768];
    const int tl = blockIdx.x >> 9;
    const int inner = blockIdx.x & 511;
    gemm_tile_body(X + (size_t)tl * 131072, Wxi, Zring + (size_t)tl * 524288,
                   inner >> 7, inner & 127, smem);
}

// ---------------- host ----------------

extern "C" void kernel_launch(void* const* d_in, const int* in_sizes, int n_in,
                              void* d_out, int out_size, void* d_ws, size_t ws_size,
                              hipStream_t stream) {
    const float* X  = (const float*)d_in[0];
    const float* Wf = (const float*)d_in[1];
    const float* bf = (const float*)d_in[2];
    const float* Wi = (const float*)d_in[3];
    const float* bi = (const float*)d_in[4];
    const float* Wg = (const float*)d_in[5];
    const float* bg = (const float*)d_in[6];
    const float* Wo = (const float*)d_in[7];
    const float* bo = (const float*)d_in[8];
    unsigned char* ws = (unsigned char*)d_ws;

    unsigned short* Wxi = (unsigned short*)(ws + WX_OFF);
    unsigned short* Whi = (unsigned short*)(ws + WH_OFF);
    unsigned short* hbuf = (unsigned short*)(ws + H_OFF);
    float* c_ws = (float*)(ws + C_OFF);
    float* outp = (float*)d_out;

    cvt_wi<<<dim3(4096), dim3(256), 0, stream>>>(Wf, Wi, Wg, Wo, Wxi, Whi);
    zero_ws<<<dim3(1024), dim3(256), 0, stream>>>((unsigned int*)(ws + H_OFF));
    hipFuncSetAttribute((const void*)lstm_step5,
                        hipFuncAttributeMaxDynamicSharedMemorySize, 98304);
    hipFuncSetAttribute((const void*)gemm_zx128,
                        hipFuncAttributeMaxDynamicSharedMemorySize, 98304);

    if (ws_size >= WS_MAIN) {
        unsigned short* Xb = (unsigned short*)(ws + XBF_OFF);
        unsigned short* Zx = (unsigned short*)(ws + ZX_OFF);
        for (int q = 0; q < 4; ++q) {
            // convert quarter of X (128 steps = 32 MiB bf16)
            cvt_x<<<dim3(8192), dim3(256), 0, stream>>>(
                X + (size_t)q * 16777216, Xb);
            for (int c2 = 0; c2 < 2; ++c2) {          // 2 chunks of 64 steps
                gemm_zx128<<<dim3(2048), dim3(256), 98304, stream>>>(
                    Xb + (size_t)c2 * 8388608, Wxi, Zx);
                for (int tl = 0; tl < 64; ++tl) {
                    const int t = q * 128 + c2 * 64 + tl;
                    const unsigned short* hp = hbuf + (size_t)(t & 1) * (BB * 1024);
                    unsigned short* hn = hbuf + (size_t)((t + 1) & 1) * (BB * 1024);
                    lstm_step5<<<dim3(256), dim3(512), 98304, stream>>>(
                        Zx + (size_t)tl * 524288, Whi, bf, bi, bg, bo,
                        hp, hn, c_ws, outp, t);
                }
            }
        }
    } else {
        // fallback: 32x32-tile gemm from f32 X, Zx ring at XBF_OFF
        unsigned short* Zx = (unsigned short*)(ws + XBF_OFF);
        int C = 4;
        const int cands[4] = {64, 16, 8, 4};
        for (int i = 0; i < 4; ++i) {
            if ((size_t)XBF_OFF + (size_t)cands[i] * 1048576u <= ws_size) { C = cands[i]; break; }
        }
        const int nchunks = TT / C;
        for (int ch = 0; ch < nchunks; ++ch) {
            gemm_zx32<<<dim3(C * 512), dim3(256), 0, stream>>>(
                X + (size_t)ch * C * 131072, Wxi, Zx);
            for (int tl = 0; tl < C; ++tl) {
                const int t = ch * C + tl;
                const unsigned short* hp = hbuf + (size_t)(t & 1) * (BB * 1024);
                unsigned short* hn = hbuf + (size_t)((t + 1) & 1) * (BB * 1024);
                lstm_step5<<<dim3(256), dim3(512), 98304, stream>>>(
                    Zx + (size_t)tl * 524288, Whi, bf, bi, bg, bo,
                    hp, hn, c_ws, outp, t);
            }
        }
    }
}

// Round 17
// 4100.532 us; speedup vs baseline: 1.0702x; 1.0380x over previous
//
#include <hip/hip_runtime.h>

// LSTM T=512,B=128,D=H=1024. R17 = R16 with the compile fix: nontemporal
// stores go through clang ext_vector f32x4 (not HIP_vector_type float4).
// Otherwise R13 verbatim (proven best, 4160us) + nt `out` stores.
// Gate interleave: n = hcol*4+gate -> f/i/g/o in lanes l^{0,1,2,3}.

#define TT 512
#define BB 128

typedef __attribute__((ext_vector_type(8))) short short8;
typedef __attribute__((ext_vector_type(4))) float f32x4;

// ws layout (main tier) — bound proven by R11/R13 passing runs
#define WX_OFF   0u                  // [4096][1024] bf16 = 8 MiB
#define WH_OFF   8388608u            // [4096][1024] bf16 = 8 MiB
#define H_OFF    16777216u           // 2 x [128][1024] bf16 = 512 KiB
#define C_OFF    17301504u           // [32][1024][4] f32 = 512 KiB (blocked)
#define XBF_OFF  17825792u           // quarter X: [128*128][1024] bf16 = 32 MiB
#define ZX_OFF   51380224u           // 64 slots x [32][4096][4] bf16 = 64 MiB
#define WS_MAIN  118489088u

__device__ __forceinline__ unsigned short f2bf(float x) {
    union { float f; unsigned int u; } a; a.f = x;
    unsigned int r = a.u + 0x7fff + ((a.u >> 16) & 1);
    return (unsigned short)(r >> 16);
}

__device__ __forceinline__ float fsig(float x) {
    float e = __expf(-x);
    return __builtin_amdgcn_rcpf(1.0f + e);
}
__device__ __forceinline__ float ftanh(float x) {
    float e = __expf(2.0f * x);
    return 1.0f - 2.0f * __builtin_amdgcn_rcpf(e + 1.0f);
}

__device__ __forceinline__ void gll16(const void* g, void* l) {
    __builtin_amdgcn_global_load_lds(
        (const __attribute__((address_space(1))) unsigned int*)g,
        (__attribute__((address_space(3))) unsigned int*)l, 16, 0, 0);
}

__device__ __forceinline__ void nt_store4(float* p, float a, float b,
                                          float c, float d) {
    f32x4 v; v.x = a; v.y = b; v.z = c; v.w = d;
    __builtin_nontemporal_store(v, (f32x4*)p);
}

// ---------------- phase 0 ----------------

__global__ __launch_bounds__(256) void cvt_wi(const float* __restrict__ Wf,
                                              const float* __restrict__ Wi,
                                              const float* __restrict__ Wg,
                                              const float* __restrict__ Wo,
                                              unsigned short* __restrict__ Wxi,
                                              unsigned short* __restrict__ Whi) {
    const int n = blockIdx.x;              // gate-col, n = hcol*4+gate
    const int k8 = threadIdx.x * 8;
    const int gate = n & 3, hcol = n >> 2;
    const float* src = ((gate == 0) ? Wf : (gate == 1) ? Wi : (gate == 2) ? Wg : Wo)
                       + (size_t)hcol * 2048 + k8;
    float4 a = *(const float4*)src;
    float4 b = *(const float4*)(src + 4);
    uint4 u;
    u.x = (unsigned)f2bf(a.x) | ((unsigned)f2bf(a.y) << 16);
    u.y = (unsigned)f2bf(a.z) | ((unsigned)f2bf(a.w) << 16);
    u.z = (unsigned)f2bf(b.x) | ((unsigned)f2bf(b.y) << 16);
    u.w = (unsigned)f2bf(b.z) | ((unsigned)f2bf(b.w) << 16);
    unsigned short* dst = (k8 < 1024) ? Wxi + (size_t)n * 1024 + k8
                                      : Whi + (size_t)n * 1024 + (k8 - 1024);
    *(uint4*)dst = u;
}

__global__ __launch_bounds__(256) void cvt_x(const float* __restrict__ X,
                                             unsigned short* __restrict__ dst) {
    size_t off = ((size_t)blockIdx.x * 256 + threadIdx.x) * 8;
    float4 a = *(const float4*)(X + off);
    float4 b = *(const float4*)(X + off + 4);
    uint4 u;
    u.x = (unsigned)f2bf(a.x) | ((unsigned)f2bf(a.y) << 16);
    u.y = (unsigned)f2bf(a.z) | ((unsigned)f2bf(a.w) << 16);
    u.z = (unsigned)f2bf(b.x) | ((unsigned)f2bf(b.y) << 16);
    u.w = (unsigned)f2bf(b.z) | ((unsigned)f2bf(b.w) << 16);
    *(uint4*)(dst + off) = u;
}

__global__ __launch_bounds__(256) void zero_ws(unsigned int* __restrict__ p) {
    p[blockIdx.x * 256 + threadIdx.x] = 0u;  // 1 MiB: h double-buffer + c
}

// ---------------- 128x128-tile Zx GEMM (R13 verbatim) ----------------------
// Grid 2048: mt = bid>>5 (one step each, 0..63), nt = bid&31.
// 256 thr / 4 waves (2x2), wave tile 64x64 = 4x4 frags. BK=64, 16 chunks.
// LDS 64KB static -> 2 blocks/CU (cross-block overlap hides drains).

__global__ __launch_bounds__(256) void gemm_zx128(
    const unsigned short* __restrict__ Xb,   // [64*128][1024] bf16 (chunk)
    const unsigned short* __restrict__ Wxi,  // [4096][1024] bf16
    unsigned short* __restrict__ Zc) {       // [64][32][4096][4] bf16
    __shared__ __align__(16) unsigned char smem[65536];

    const int tid = threadIdx.x;
    const int l = tid & 63;
    const int w = tid >> 6;
    const int wr = w >> 1, wc = w & 1;
    const int mt = blockIdx.x >> 5;
    const int nt = blockIdx.x & 31;
    const int lq = l >> 4, sp = l & 15;

    const int srow = l >> 3;
    const int sslot = l & 7;
    const unsigned short* As[4];
    const unsigned short* Bs[4];
    unsigned dstb[4];
#pragma unroll
    for (int q = 0; q < 4; ++q) {
        const int seg = w * 4 + q;
        const int row = seg * 8 + srow;
        const unsigned so = (unsigned)((sslot ^ (row & 7)) * 8);
        As[q] = Xb + (size_t)(mt * 128 + row) * 1024 + so;
        Bs[q] = Wxi + (size_t)(nt * 128 + row) * 1024 + so;
        dstb[q] = (unsigned)(seg * 1024);     // wave-uniform; HW adds lane*16
    }

    auto stage = [&](int c, int buf) {
        unsigned char* Ab = smem + buf * 16384;
        unsigned char* Bb = smem + 32768 + buf * 16384;
#pragma unroll
        for (int q = 0; q < 4; ++q) {
            gll16(As[q] + c * 64, Ab + dstb[q]);
            gll16(Bs[q] + c * 64, Bb + dstb[q]);
        }
    };

    f32x4 acc[4][4];
#pragma unroll
    for (int m = 0; m < 4; ++m)
#pragma unroll
        for (int n = 0; n < 4; ++n) acc[m][n] = {0.f, 0.f, 0.f, 0.f};

    auto compute = [&](int buf) {
        const unsigned char* Ab = smem + buf * 16384;
        const unsigned char* Bb = smem + 32768 + buf * 16384;
        short8 af[4][2], bfr[4][2];
#pragma unroll
        for (int m = 0; m < 4; ++m) {
            const int ar = wr * 64 + m * 16 + sp;
            const unsigned abase = (unsigned)(ar * 128), axor = (unsigned)((ar & 7) << 4);
#pragma unroll
            for (int k2 = 0; k2 < 2; ++k2)
                af[m][k2] = *(const short8*)(Ab + abase +
                            (((unsigned)(k2 * 64 + lq * 16)) ^ axor));
        }
#pragma unroll
        for (int n = 0; n < 4; ++n) {
            const int br = wc * 64 + n * 16 + sp;
            const unsigned bbase = (unsigned)(br * 128), bxor = (unsigned)((br & 7) << 4);
#pragma unroll
            for (int k2 = 0; k2 < 2; ++k2)
                bfr[n][k2] = *(const short8*)(Bb + bbase +
                             (((unsigned)(k2 * 64 + lq * 16)) ^ bxor));
        }
#pragma unroll
        for (int m = 0; m < 4; ++m)
#pragma unroll
            for (int n = 0; n < 4; ++n) {
                acc[m][n] = __builtin_amdgcn_mfma_f32_16x16x32_bf16(
                    af[m][0], bfr[n][0], acc[m][n], 0, 0, 0);
                acc[m][n] = __builtin_amdgcn_mfma_f32_16x16x32_bf16(
                    af[m][1], bfr[n][1], acc[m][n], 0, 0, 0);
            }
    };

    stage(0, 0);
    __syncthreads();
    for (int c = 0; c < 16; ++c) {
        const int buf = c & 1;
        if (c < 15) stage(c + 1, buf ^ 1);
        compute(buf);
        __syncthreads();
    }

#pragma unroll
    for (int m = 0; m < 4; ++m) {
        const int ri = wr * 64 + m * 16 + lq * 4;   // row within step (mt)
#pragma unroll
        for (int n = 0; n < 4; ++n) {
            const int ncol = nt * 128 + wc * 64 + n * 16 + sp;
            f32x4 z4 = acc[m][n];
            uint2 z2;
            z2.x = (unsigned)f2bf(z4[0]) | ((unsigned)f2bf(z4[1]) << 16);
            z2.y = (unsigned)f2bf(z4[2]) | ((unsigned)f2bf(z4[3]) << 16);
            *(uint2*)(Zc + (size_t)mt * 524288 + (size_t)(ri >> 2) * 16384 +
                      (size_t)ncol * 4) = z2;
        }
    }
}

// ---------------- per-timestep h-GEMM (R13 verbatim + nt out stores) -------
// grid 256: rg = bid>>7 (0..1, 64 rows), cg = bid&127 (32 gate-cols).
// 512 thr / 8 waves: wm = w>>1 (16-row strip), wn = w&1 (16-col strip).
// 8 K-chunks of 128; depth-3 counted vmcnt, 3 glls/wave/stage.
// LDS dynamic 96KB: A 4x16KB @0, B 4x8KB @65536. Waits 6,6,6,6,6,6,3,0.

__global__ __launch_bounds__(512) void lstm_step5(
    const unsigned short* __restrict__ Zslot,   // [32][4096][4] bf16 blocked
    const unsigned short* __restrict__ Whi,     // [4096][1024] bf16
    const float* __restrict__ bfp, const float* __restrict__ bip,
    const float* __restrict__ bgp, const float* __restrict__ bop,
    const unsigned short* __restrict__ h_prev,  // [128][1024] bf16
    unsigned short* __restrict__ h_next,        // [128][1024] bf16
    float* __restrict__ c_ws,                   // [32][1024][4] f32 blocked
    float* __restrict__ out, int t) {
    extern __shared__ __align__(16) unsigned char smem[];

    const int tid = threadIdx.x;
    const int l = tid & 63;
    const int w = tid >> 6;              // 0..7
    const int wm = w >> 1, wn = w & 1;
    const int rg = blockIdx.x >> 7;      // 0..1
    const int cg = blockIdx.x & 127;
    const int lq = l >> 4, sp = l & 15;
    const int g0 = l & 3;
    const int n = cg * 32 + wn * 16 + sp;
    const int j = n >> 2;
    const int j0 = cg * 8 + wn * 4;
    const int cidx = sp >> 2;
    const int srcb = l & 48;
    const int rbase = rg * 64 + wm * 16 + lq * 4;

    // preloads (3 VMEM/thread)
    const float* bp = (g0 == 0) ? bfp : (g0 == 1) ? bip : (g0 == 2) ? bgp : bop;
    const float biasv = bp[j];
    uint2 zu = *(const uint2*)(Zslot + ((size_t)(rbase >> 2) * 4096 + n) * 4);
    float4 cp4 = *(const float4*)(c_ws + ((size_t)(rbase >> 2) * 1024 + j) * 4);

    f32x4 acc_a = {0.f, 0.f, 0.f, 0.f};
    f32x4 acc_b = {0.f, 0.f, 0.f, 0.f};

    // A staging: 16 segs of 1KB (4 rows x 256B); wave w -> segs w*2, w*2+1.
    const int ar0 = (w * 2 + 0) * 4 + (l >> 4);
    const int ar1 = (w * 2 + 1) * 4 + (l >> 4);
    const unsigned short* hsrc0 =
        h_prev + (size_t)(rg * 64 + ar0) * 1024 + ((sp ^ (ar0 & 7)) * 8);
    const unsigned short* hsrc1 =
        h_prev + (size_t)(rg * 64 + ar1) * 1024 + ((sp ^ (ar1 & 7)) * 8);
    // B staging: 8 segs of 1KB; wave w -> seg w; brow = w*4 + (l>>4).
    const int brw = w * 4 + (l >> 4);
    const unsigned short* wsrc =
        Whi + (size_t)(cg * 32 + brw) * 1024 + ((sp ^ (brw & 7)) * 8);

    auto stage = [&](int c, int buf) {  // 3 glls/wave
        unsigned char* Ab = smem + buf * 16384;
        unsigned char* Bb = smem + 65536 + buf * 8192;
        gll16(hsrc0 + c * 128, Ab + (w * 2 + 0) * 1024);
        gll16(hsrc1 + c * 128, Ab + (w * 2 + 1) * 1024);
        gll16(wsrc + c * 128, Bb + w * 1024);
    };
    auto compute = [&](int buf) {
        const unsigned char* Ab = smem + buf * 16384;
        const unsigned char* Bb = smem + 65536 + buf * 8192;
        const int ar = wm * 16 + sp;
        const int br = wn * 16 + sp;
        const unsigned abase = (unsigned)(ar * 256), axor = (unsigned)((ar & 7) << 4);
        const unsigned bbase = (unsigned)(br * 256), bxor = (unsigned)((br & 7) << 4);
#pragma unroll
        for (int ks = 0; ks < 4; ++ks) {
            const unsigned kk2 = (unsigned)((ks * 4 + lq) << 4);
            short8 a = *(const short8*)(Ab + abase + (kk2 ^ axor));
            short8 b = *(const short8*)(Bb + bbase + (kk2 ^ bxor));
            if (ks & 1) acc_b = __builtin_amdgcn_mfma_f32_16x16x32_bf16(a, b, acc_b, 0, 0, 0);
            else        acc_a = __builtin_amdgcn_mfma_f32_16x16x32_bf16(a, b, acc_a, 0, 0, 0);
        }
    };

    stage(0, 0); stage(1, 1); stage(2, 2);

#define PH(c, WN, DO_STAGE)                                                   \
    asm volatile("s_waitcnt vmcnt(" #WN ") lgkmcnt(0)" ::: "memory");         \
    __builtin_amdgcn_sched_barrier(0);                                        \
    __builtin_amdgcn_s_barrier();                                             \
    if (DO_STAGE) stage((c) + 3, ((c) + 3) & 3);                              \
    compute((c) & 3);

    PH(0, 6, 1)
    PH(1, 6, 1)
    PH(2, 6, 1)
    PH(3, 6, 1)
    PH(4, 6, 1)
    PH(5, 6, 0)
    PH(6, 3, 0)
    PH(7, 0, 0)
#undef PH

    // epilogue: z = zh + zx + bias
    f32x4 z4 = acc_a + acc_b;
    z4[0] += __uint_as_float(zu.x << 16) + biasv;
    z4[1] += __uint_as_float(zu.x & 0xffff0000u) + biasv;
    z4[2] += __uint_as_float(zu.y << 16) + biasv;
    z4[3] += __uint_as_float(zu.y & 0xffff0000u) + biasv;
    float cpv[4] = {cp4.x, cp4.y, cp4.z, cp4.w};
    float hhv[4], ccv[4];
#pragma unroll
    for (int r = 0; r < 4; ++r) {
        float z = z4[r];
        float v1 = __shfl_xor(z, 1);
        float v2 = __shfl_xor(z, 2);
        float v3 = __shfl_xor(z, 3);
        float fg = fsig(z);
        float ig = fsig(v1);
        float gg = ftanh(v2);
        float og = fsig(v3);
        float cc = fg * cpv[r] + ig * gg;   // meaningful in g0==0 lanes
        ccv[r] = cc;
        hhv[r] = og * ftanh(cc);
    }
    if (g0 == 0) {  // blocked c store, no transpose
        float4 q4; q4.x = ccv[0]; q4.y = ccv[1]; q4.z = ccv[2]; q4.w = ccv[3];
        *(float4*)(c_ws + ((size_t)(rbase >> 2) * 1024 + j) * 4) = q4;
    }
#pragma unroll
    for (int r = 0; r < 4; ++r) {
        float e0 = __shfl(hhv[r], srcb + 0);
        float e1 = __shfl(hhv[r], srcb + 4);
        float e2 = __shfl(hhv[r], srcb + 8);
        float e3 = __shfl(hhv[r], srcb + 12);
        if (g0 == 0 && cidx == r) {
            const int row = rbase + r;
            nt_store4(&out[((size_t)t * BB + row) * 1024 + j0], e0, e1, e2, e3);
            uint2 h2;
            h2.x = (unsigned)f2bf(e0) | ((unsigned)f2bf(e1) << 16);
            h2.y = (unsigned)f2bf(e2) | ((unsigned)f2bf(e3) << 16);
            *(uint2*)(&h_next[(size_t)row * 1024 + j0]) = h2;
        }
        if (t == TT - 1) {
            float d0 = __shfl(ccv[r], srcb + 0);
            float d1 = __shfl(ccv[r], srcb + 4);
            float d2 = __shfl(ccv[r], srcb + 8);
            float d3 = __shfl(ccv[r], srcb + 12);
            if (g0 == 0 && cidx == r) {
                const int row = rbase + r;
                nt_store4(&out[(size_t)TT * BB * 1024 + (size_t)row * 1024 + j0],
                          e0, e1, e2, e3);
                nt_store4(&out[(size_t)TT * BB * 1024 + (size_t)BB * 1024 +
                               (size_t)row * 1024 + j0], d0, d1, d2, d3);
            }
        }
    }
}

// ---------------- fallback 32x32-tile Zx body (R9-proven) ----------------

__device__ __forceinline__ void gemm_tile_body(
    const float* __restrict__ Xt, const unsigned short* __restrict__ Wxi,
    unsigned short* __restrict__ Zslot, int mt, int cg, unsigned char* smem) {
    const int tid = threadIdx.x;
    const int l = tid & 63;
    const int w = tid >> 6;
    const int wr = w >> 1, wc = w & 1;
    const int lq = l >> 4, sp = l & 15;

    f32x4 acc_a = {0.f, 0.f, 0.f, 0.f};
    f32x4 acc_b = {0.f, 0.f, 0.f, 0.f};

    const int xrow = tid >> 3;
    const int xs = (tid & 7) * 2;
    const float* xsrc = Xt + (size_t)(mt * 32 + xrow) * 1024 + xs * 8;
    const unsigned xw0 = (unsigned)(xrow * 256 + ((xs * 16) ^ ((xrow & 7) << 4)));
    const unsigned xw1 = (unsigned)(xrow * 256 + (((xs + 1) * 16) ^ ((xrow & 7) << 4)));
    float4 xv0, xv1, xv2, xv3;

    const int bn0 = w * 8 + lq, bn1 = bn0 + 4;
    const unsigned short* wsrc0 = Wxi + (size_t)(cg * 32 + bn0) * 1024 + (sp ^ (bn0 & 7)) * 8;
    const unsigned short* wsrc1 = Wxi + (size_t)(cg * 32 + bn1) * 1024 + (sp ^ (bn1 & 7)) * 8;

    auto load_x = [&](int c) {
        const float* p = xsrc + c * 128;
        xv0 = *(const float4*)(p);     xv1 = *(const float4*)(p + 4);
        xv2 = *(const float4*)(p + 8); xv3 = *(const float4*)(p + 12);
    };
    auto write_x = [&](int buf) {
        unsigned char* Ab = smem + (buf ? 8192 : 0);
        uint4 u0, u1;
        u0.x = (unsigned)f2bf(xv0.x) | ((unsigned)f2bf(xv0.y) << 16);
        u0.y = (unsigned)f2bf(xv0.z) | ((unsigned)f2bf(xv0.w) << 16);
        u0.z = (unsigned)f2bf(xv1.x) | ((unsigned)f2bf(xv1.y) << 16);
        u0.w = (unsigned)f2bf(xv1.z) | ((unsigned)f2bf(xv1.w) << 16);
        u1.x = (unsigned)f2bf(xv2.x) | ((unsigned)f2bf(xv2.y) << 16);
        u1.y = (unsigned)f2bf(xv2.z) | ((unsigned)f2bf(xv2.w) << 16);
        u1.z = (unsigned)f2bf(xv3.x) | ((unsigned)f2bf(xv3.y) << 16);
        u1.w = (unsigned)f2bf(xv3.z) | ((unsigned)f2bf(xv3.w) << 16);
        *(uint4*)(Ab + xw0) = u0; *(uint4*)(Ab + xw1) = u1;
    };
    auto stage_B = [&](int c, int buf) {
        unsigned char* Bb = smem + 16384 + (buf ? 8192 : 0);
        gll16(wsrc0 + c * 128, Bb + (w * 8) * 256);
        gll16(wsrc1 + c * 128, Bb + (w * 8 + 4) * 256);
    };
    auto compute = [&](int buf) {
        const unsigned char* Ab = smem + (buf ? 8192 : 0);
        const unsigned char* Bb = smem + 16384 + (buf ? 8192 : 0);
        const int ar = wr * 16 + sp;
        const int br = wc * 16 + sp;
        const unsigned abase = (unsigned)(ar * 256), axor = (unsigned)((ar & 7) << 4);
        const unsigned bbase = (unsigned)(br * 256), bxor = (unsigned)((br & 7) << 4);
#pragma unroll
        for (int ks = 0; ks < 4; ++ks) {
            const unsigned kk2 = (unsigned)((ks * 4 + lq) << 4);
            short8 a = *(const short8*)(Ab + abase + (kk2 ^ axor));
            short8 b = *(const short8*)(Bb + bbase + (kk2 ^ bxor));
            if (ks & 1) acc_b = __builtin_amdgcn_mfma_f32_16x16x32_bf16(a, b, acc_b, 0, 0, 0);
            else        acc_a = __builtin_amdgcn_mfma_f32_16x16x32_bf16(a, b, acc_a, 0, 0, 0);
        }
    };

    load_x(0); stage_B(0, 0); write_x(0);
    __syncthreads();
    for (int c = 0; c < 8; ++c) {
        const int buf = c & 1, nbuf = buf ^ 1;
        if (c < 7) { load_x(c + 1); stage_B(c + 1, nbuf); }
        compute(buf);
        if (c < 7) write_x(nbuf);
        __syncthreads();
    }

    const int rowb = mt * 32 + wr * 16 + lq * 4;
    const int n = cg * 32 + wc * 16 + sp;
    f32x4 z4 = acc_a + acc_b;
    uint2 z2;
    z2.x = (unsigned)f2bf(z4[0]) | ((unsigned)f2bf(z4[1]) << 16);
    z2.y = (unsigned)f2bf(z4[2]) | ((unsigned)f2bf(z4[3]) << 16);
    *(uint2*)(Zslot + ((size_t)(rowb >> 2) * 4096 + n) * 4) = z2;
}

__global__ __launch_bounds__(256) void gemm_zx32(
    const float* __restrict__ X, const unsigned short* __restrict__ Wxi,
    unsigned short* __restrict__ Zring) {
    __shared__ __align__(16) unsigned char smem[32768];
    const int tl = blockIdx.x >> 9;
    const int inner = blockIdx.x & 511;
    gemm_tile_body(X + (size_t)tl * 131072, Wxi, Zring + (size_t)tl * 524288,
                   inner >> 7, inner & 127, smem);
}

// ---------------- host ----------------

extern "C" void kernel_launch(void* const* d_in, const int* in_sizes, int n_in,
                              void* d_out, int out_size, void* d_ws, size_t ws_size,
                              hipStream_t stream) {
    const float* X  = (const float*)d_in[0];
    const float* Wf = (const float*)d_in[1];
    const float* bf = (const float*)d_in[2];
    const float* Wi = (const float*)d_in[3];
    const float* bi = (const float*)d_in[4];
    const float* Wg = (const float*)d_in[5];
    const float* bg = (const float*)d_in[6];
    const float* Wo = (const float*)d_in[7];
    const float* bo = (const float*)d_in[8];
    unsigned char* ws = (unsigned char*)d_ws;

    unsigned short* Wxi = (unsigned short*)(ws + WX_OFF);
    unsigned short* Whi = (unsigned short*)(ws + WH_OFF);
    unsigned short* hbuf = (unsigned short*)(ws + H_OFF);
    float* c_ws = (float*)(ws + C_OFF);
    float* outp = (float*)d_out;

    cvt_wi<<<dim3(4096), dim3(256), 0, stream>>>(Wf, Wi, Wg, Wo, Wxi, Whi);
    zero_ws<<<dim3(1024), dim3(256), 0, stream>>>((unsigned int*)(ws + H_OFF));
    (void)hipFuncSetAttribute((const void*)lstm_step5,
                              hipFuncAttributeMaxDynamicSharedMemorySize, 98304);

    if (ws_size >= WS_MAIN) {
        unsigned short* Xb = (unsigned short*)(ws + XBF_OFF);
        unsigned short* Zx = (unsigned short*)(ws + ZX_OFF);
        for (int q = 0; q < 4; ++q) {
            // convert quarter of X (128 steps = 32 MiB bf16)
            cvt_x<<<dim3(8192), dim3(256), 0, stream>>>(
                X + (size_t)q * 16777216, Xb);
            for (int c2 = 0; c2 < 2; ++c2) {          // 2 chunks of 64 steps
                gemm_zx128<<<dim3(2048), dim3(256), 0, stream>>>(
                    Xb + (size_t)c2 * 8388608, Wxi, Zx);
                for (int tl = 0; tl < 64; ++tl) {
                    const int t = q * 128 + c2 * 64 + tl;
                    const unsigned short* hp = hbuf + (size_t)(t & 1) * (BB * 1024);
                    unsigned short* hn = hbuf + (size_t)((t + 1) & 1) * (BB * 1024);
                    lstm_step5<<<dim3(256), dim3(512), 98304, stream>>>(
                        Zx + (size_t)tl * 524288, Whi, bf, bi, bg, bo,
                        hp, hn, c_ws, outp, t);
                }
            }
        }
    } else {
        // fallback: 32x32-tile gemm from f32 X, Zx ring at XBF_OFF
        unsigned short* Zx = (unsigned short*)(ws + XBF_OFF);
        int C = 4;
        const int cands[4] = {64, 16, 8, 4};
        for (int i = 0; i < 4; ++i) {
            if ((size_t)XBF_OFF + (size_t)cands[i] * 1048576u <= ws_size) { C = cands[i]; break; }
        }
        const int nchunks = TT / C;
        for (int ch = 0; ch < nchunks; ++ch) {
            gemm_zx32<<<dim3(C * 512), dim3(256), 0, stream>>>(
                X + (size_t)ch * C * 131072, Wxi, Zx);
            for (int tl = 0; tl < C; ++tl) {
                const int t = ch * C + tl;
                const unsigned short* hp = hbuf + (size_t)(t & 1) * (BB * 1024);
                unsigned short* hn = hbuf + (size_t)((t + 1) & 1) * (BB * 1024);
                lstm_step5<<<dim3(256), dim3(512), 98304, stream>>>(
                    Zx + (size_t)tl * 524288, Whi, bf, bi, bg, bo,
                    hp, hn, c_ws, outp, t);
            }
        }
    }
}